// Round 1
// baseline (2348.936 us; speedup 1.0000x reference)
//
#include <hip/hip_runtime.h>
#include <hip/hip_bf16.h>
#include <cstdint>

#define N_NODES 50000
#define N_EDGES 800000

__device__ __forceinline__ void atomicMaxF32(float* addr, float val) {
    if (val >= 0.f) atomicMax(reinterpret_cast<int*>(addr), __float_as_int(val));
    else atomicMin(reinterpret_cast<unsigned int*>(addr), __float_as_uint(val));
}

// feat = X @ W  (X:[N,DIN], W:[DIN,DOUT]) and el/er = sum_f feat*attn over last F
template<int DIN, int DOUT, int F>
__global__ __launch_bounds__(DOUT) void gemm_attn(
    const float* __restrict__ X, const float* __restrict__ W,
    const float* __restrict__ al, const float* __restrict__ ar,
    float* __restrict__ feat, float* __restrict__ el, float* __restrict__ er, int N)
{
    constexpr int RPT = 8;
    constexpr int H = DOUT / F;
    __shared__ float xs[RPT][DIN];
    const int j = threadIdx.x;
    const int row0 = blockIdx.x * RPT;

    for (int idx = j; idx < RPT * DIN; idx += DOUT) {
        int r = idx / DIN, k = idx - r * DIN;
        int row = row0 + r;
        xs[r][k] = (row < N) ? X[(size_t)row * DIN + k] : 0.f;
    }
    __syncthreads();

    float acc[RPT];
#pragma unroll
    for (int r = 0; r < RPT; ++r) acc[r] = 0.f;

    for (int k = 0; k < DIN; k += 4) {
        float w0 = W[(size_t)(k + 0) * DOUT + j];
        float w1 = W[(size_t)(k + 1) * DOUT + j];
        float w2 = W[(size_t)(k + 2) * DOUT + j];
        float w3 = W[(size_t)(k + 3) * DOUT + j];
#pragma unroll
        for (int r = 0; r < RPT; ++r) {
            const float4 xv = *reinterpret_cast<const float4*>(&xs[r][k]);
            acc[r] = fmaf(xv.x, w0, acc[r]);
            acc[r] = fmaf(xv.y, w1, acc[r]);
            acc[r] = fmaf(xv.z, w2, acc[r]);
            acc[r] = fmaf(xv.w, w3, acc[r]);
        }
    }

    const float alv = al[j];
    const float arv = ar[j];
#pragma unroll
    for (int r = 0; r < RPT; ++r) {
        int row = row0 + r;
        float pl = acc[r] * alv;
        float pr = acc[r] * arv;
#pragma unroll
        for (int off = F / 2; off >= 1; off >>= 1) {
            pl += __shfl_xor(pl, off, F);
            pr += __shfl_xor(pr, off, F);
        }
        if (row < N) {
            feat[(size_t)row * DOUT + j] = acc[r];
            if ((j & (F - 1)) == 0) {
                int h = j / F;
                el[(size_t)row * H + h] = pl;
                er[(size_t)row * H + h] = pr;
            }
        }
    }
}

__global__ void init_layer(float* __restrict__ m, float* __restrict__ s,
                           float* __restrict__ acc, int nh, int nacc)
{
    int i = blockIdx.x * blockDim.x + threadIdx.x;
    if (i < nh) { m[i] = -1e30f; s[i] = 0.f; }
    if (i < nacc) acc[i] = 0.f;
}

template<int H>
__global__ void edge_logits_max(const int* __restrict__ src, const int* __restrict__ dst,
                                const float* __restrict__ el, const float* __restrict__ er,
                                float* __restrict__ ebuf, float* __restrict__ m)
{
    int e = blockIdx.x * blockDim.x + threadIdx.x;
    if (e >= N_EDGES) return;
    int s = src[e], d = dst[e];
    float ev[H];
#pragma unroll
    for (int h = 0; h < H; ++h) {
        float v = el[(size_t)s * H + h] + er[(size_t)d * H + h];
        ev[h] = (v > 0.f) ? v : 0.2f * v;   // leaky_relu 0.2
    }
#pragma unroll
    for (int h = 0; h < H; ++h) {
        ebuf[(size_t)e * H + h] = ev[h];
        atomicMaxF32(&m[(size_t)d * H + h], ev[h]);
    }
}

template<int H>
__global__ void edge_exp_sum(const int* __restrict__ dst, float* __restrict__ ebuf,
                             const float* __restrict__ m, float* __restrict__ sden)
{
    int e = blockIdx.x * blockDim.x + threadIdx.x;
    if (e >= N_EDGES) return;
    int d = dst[e];
#pragma unroll
    for (int h = 0; h < H; ++h) {
        float ex = __expf(ebuf[(size_t)e * H + h] - m[(size_t)d * H + h]);
        ebuf[(size_t)e * H + h] = ex;
        atomicAdd(&sden[(size_t)d * H + h], ex);
    }
}

template<int H, int F>
__global__ void edge_aggregate(const int* __restrict__ src, const int* __restrict__ dst,
                               const float* __restrict__ ebuf, const float* __restrict__ sden,
                               const float* __restrict__ feat, float* __restrict__ acc)
{
    constexpr int D = H * F;
    int i = blockIdx.x * blockDim.x + threadIdx.x;   // over E*D
    int e = i / D;
    int c = i - e * D;
    if (e >= N_EDGES) return;
    int h = c / F;
    int d = dst[e], s = src[e];
    float alpha = ebuf[(size_t)e * H + h] / sden[(size_t)d * H + h];
    atomicAdd(&acc[(size_t)d * D + c], feat[(size_t)s * D + c] * alpha);
}

template<int D, bool ACT>
__global__ void node_finalize(const float* __restrict__ acc, const float* __restrict__ bias,
                              float* __restrict__ out)
{
    int i = blockIdx.x * blockDim.x + threadIdx.x;
    if (i >= N_NODES * D) return;
    int c = i & (D - 1);
    float v = acc[i] + bias[c];
    if (ACT) v = (v > 0.f) ? v : expm1f(v);   // ELU alpha=1
    out[i] = v;
}

extern "C" void kernel_launch(void* const* d_in, const int* in_sizes, int n_in,
                              void* d_out, int out_size, void* d_ws, size_t ws_size,
                              hipStream_t stream)
{
    const float* x   = (const float*)d_in[0];
    const int*   src = (const int*)d_in[1];
    const int*   dst = (const int*)d_in[2];
    const float* W0  = (const float*)d_in[3];
    const float* al0 = (const float*)d_in[4];
    const float* ar0 = (const float*)d_in[5];
    const float* b0  = (const float*)d_in[6];
    const float* W1  = (const float*)d_in[7];
    const float* al1 = (const float*)d_in[8];
    const float* ar1 = (const float*)d_in[9];
    const float* b1  = (const float*)d_in[10];
    const float* W2  = (const float*)d_in[11];
    const float* al2 = (const float*)d_in[12];
    const float* ar2 = (const float*)d_in[13];
    const float* b2  = (const float*)d_in[14];
    float* out = (float*)d_out;

    const int N = N_NODES, E = N_EDGES;
    float* ws   = (float*)d_ws;
    float* feat = ws;                       // N*128
    float* elb  = feat + (size_t)N * 128;   // N*8
    float* erb  = elb + (size_t)N * 8;      // N*8
    float* mbf  = erb + (size_t)N * 8;      // N*8
    float* sbf  = mbf + (size_t)N * 8;      // N*8
    float* ebf  = sbf + (size_t)N * 8;      // E*8
    float* accb = ebf + (size_t)E * 8;      // N*128
    float* hbuf = accb + (size_t)N * 128;   // N*128

    const int TB = 256;
    const int gb_rows  = (N + 7) / 8;            // 6250
    const int gb_edges = (E + TB - 1) / TB;      // 3125
    const int gb_n128  = (N * 128 + TB - 1) / TB;
    const int gb_n64   = (N * 64 + TB - 1) / TB;

    // ---------------- layer 0: 256 -> 8 heads x 16, ELU ----------------
    gemm_attn<256, 128, 16><<<gb_rows, 128, 0, stream>>>(x, W0, al0, ar0, feat, elb, erb, N);
    init_layer<<<gb_n128, TB, 0, stream>>>(mbf, sbf, accb, N * 8, N * 128);
    edge_logits_max<8><<<gb_edges, TB, 0, stream>>>(src, dst, elb, erb, ebf, mbf);
    edge_exp_sum<8><<<gb_edges, TB, 0, stream>>>(dst, ebf, mbf, sbf);
    edge_aggregate<8, 16><<<E / 2, TB, 0, stream>>>(src, dst, ebf, sbf, feat, accb);
    node_finalize<128, true><<<gb_n128, TB, 0, stream>>>(accb, b0, hbuf);

    // ---------------- layer 1: 128 -> 8 heads x 16, ELU ----------------
    gemm_attn<128, 128, 16><<<gb_rows, 128, 0, stream>>>(hbuf, W1, al1, ar1, feat, elb, erb, N);
    init_layer<<<gb_n128, TB, 0, stream>>>(mbf, sbf, accb, N * 8, N * 128);
    edge_logits_max<8><<<gb_edges, TB, 0, stream>>>(src, dst, elb, erb, ebf, mbf);
    edge_exp_sum<8><<<gb_edges, TB, 0, stream>>>(dst, ebf, mbf, sbf);
    edge_aggregate<8, 16><<<E / 2, TB, 0, stream>>>(src, dst, ebf, sbf, feat, accb);
    node_finalize<128, true><<<gb_n128, TB, 0, stream>>>(accb, b1, hbuf);

    // ---------------- layer 2: 128 -> 1 head x 64, no act --------------
    gemm_attn<128, 64, 64><<<gb_rows, 64, 0, stream>>>(hbuf, W2, al2, ar2, feat, elb, erb, N);
    init_layer<<<gb_n128, TB, 0, stream>>>(mbf, sbf, accb, N * 1, N * 64);
    edge_logits_max<1><<<gb_edges, TB, 0, stream>>>(src, dst, elb, erb, ebf, mbf);
    edge_exp_sum<1><<<gb_edges, TB, 0, stream>>>(dst, ebf, mbf, sbf);
    edge_aggregate<1, 64><<<E / 4, TB, 0, stream>>>(src, dst, ebf, sbf, feat, accb);
    node_finalize<64, false><<<gb_n64, TB, 0, stream>>>(accb, b2, out);
}

// Round 2
// 609.034 us; speedup vs baseline: 3.8568x; 3.8568x over previous
//
#include <hip/hip_runtime.h>
#include <hip/hip_bf16.h>
#include <cstdint>

#define N_NODES 50000
#define N_EDGES 800000

// ---------------------------------------------------------------------------
// feat = X @ W  (X:[N,DIN], W:[DIN,DOUT]) and el/er = sum_f feat*attn over F
template<int DIN, int DOUT, int F>
__global__ __launch_bounds__(DOUT) void gemm_attn(
    const float* __restrict__ X, const float* __restrict__ W,
    const float* __restrict__ al, const float* __restrict__ ar,
    float* __restrict__ feat, float* __restrict__ el, float* __restrict__ er, int N)
{
    constexpr int RPT = 8;
    constexpr int H = DOUT / F;
    __shared__ float xs[RPT][DIN];
    const int j = threadIdx.x;
    const int row0 = blockIdx.x * RPT;

    for (int idx = j; idx < RPT * DIN; idx += DOUT) {
        int r = idx / DIN, k = idx - r * DIN;
        int row = row0 + r;
        xs[r][k] = (row < N) ? X[(size_t)row * DIN + k] : 0.f;
    }
    __syncthreads();

    float acc[RPT];
#pragma unroll
    for (int r = 0; r < RPT; ++r) acc[r] = 0.f;

    for (int k = 0; k < DIN; k += 4) {
        float w0 = W[(size_t)(k + 0) * DOUT + j];
        float w1 = W[(size_t)(k + 1) * DOUT + j];
        float w2 = W[(size_t)(k + 2) * DOUT + j];
        float w3 = W[(size_t)(k + 3) * DOUT + j];
#pragma unroll
        for (int r = 0; r < RPT; ++r) {
            const float4 xv = *reinterpret_cast<const float4*>(&xs[r][k]);
            acc[r] = fmaf(xv.x, w0, acc[r]);
            acc[r] = fmaf(xv.y, w1, acc[r]);
            acc[r] = fmaf(xv.z, w2, acc[r]);
            acc[r] = fmaf(xv.w, w3, acc[r]);
        }
    }

    const float alv = al[j];
    const float arv = ar[j];
#pragma unroll
    for (int r = 0; r < RPT; ++r) {
        int row = row0 + r;
        float pl = acc[r] * alv;
        float pr = acc[r] * arv;
#pragma unroll
        for (int off = F / 2; off >= 1; off >>= 1) {
            pl += __shfl_xor(pl, off, F);
            pr += __shfl_xor(pr, off, F);
        }
        if (row < N) {
            feat[(size_t)row * DOUT + j] = acc[r];
            if ((j & (F - 1)) == 0) {
                int h = j / F;
                el[(size_t)row * H + h] = pl;
                er[(size_t)row * H + h] = pr;
            }
        }
    }
}

// ---------------------------------------------------------------------------
// CSR build (dst-sorted), shared by all 3 layers
__global__ void zero_ints(int* __restrict__ a, int n)
{
    int i = blockIdx.x * blockDim.x + threadIdx.x;
    if (i < n) a[i] = 0;
}

__global__ void hist_deg(const int* __restrict__ dst, int* __restrict__ deg)
{
    int e = blockIdx.x * blockDim.x + threadIdx.x;
    if (e < N_EDGES) atomicAdd(&deg[dst[e]], 1);
}

// single block, 1024 threads: exclusive scan of deg[0..n) -> offs[0..n]
__global__ __launch_bounds__(1024) void scan_offsets(
    const int* __restrict__ deg, int* __restrict__ offs, int n)
{
    __shared__ int wtot[16], wincl[16];
    __shared__ int carry_s;
    const int tid = threadIdx.x;
    const int lane = tid & 63, wid = tid >> 6;
    if (tid == 0) carry_s = 0;
    __syncthreads();
    for (int base = 0; base < n; base += 1024) {
        int i = base + tid;
        int v = (i < n) ? deg[i] : 0;
        int x = v;
#pragma unroll
        for (int off = 1; off < 64; off <<= 1) {
            int t = __shfl_up(x, off);
            if (lane >= off) x += t;
        }
        if (lane == 63) wtot[wid] = x;
        __syncthreads();
        if (tid < 16) {
            int wx = wtot[tid];
#pragma unroll
            for (int off = 1; off < 16; off <<= 1) {
                int t = __shfl_up(wx, off);
                if (tid >= off) wx += t;
            }
            wincl[tid] = wx;
        }
        __syncthreads();
        int waveExcl = (wid == 0) ? 0 : wincl[wid - 1];
        if (i < n) offs[i] = carry_s + waveExcl + (x - v);
        int total = wincl[15];
        __syncthreads();
        if (tid == 0) carry_s += total;
        __syncthreads();
    }
    if (threadIdx.x == 0) offs[n] = carry_s;
}

__global__ void build_csr(const int* __restrict__ src, const int* __restrict__ dst,
                          const int* __restrict__ offs, int* __restrict__ cursor,
                          int* __restrict__ csr_src)
{
    int e = blockIdx.x * blockDim.x + threadIdx.x;
    if (e >= N_EDGES) return;
    int d = dst[e];
    int p = offs[d] + atomicAdd(&cursor[d], 1);
    csr_src[p] = src[e];
}

// ---------------------------------------------------------------------------
// Per-dst-node fused softmax + aggregation + bias + activation.
// One wave per node; 4 waves (256 threads) per block.
template<int H, int F, bool ACT>
__global__ __launch_bounds__(256) void node_softmax_agg(
    const int* __restrict__ offs, const int* __restrict__ csr_src,
    const float* __restrict__ el, const float* __restrict__ er,
    const float* __restrict__ feat, const float* __restrict__ bias,
    float* __restrict__ out, int N)
{
    constexpr int D = H * F;
    constexpr int CPT = D / 64;     // components per lane (2 or 1)
    constexpr int EPC = 64 / H;     // edges per chunk (8 or 64)

    const int wid = threadIdx.x >> 6;
    const int lane = threadIdx.x & 63;
    const int n = blockIdx.x * 4 + wid;
    if (n >= N) return;

    const int beg = offs[n];
    const int deg = offs[n + 1] - beg;

    const int h = lane % H;
    const int esub = lane / H;
    const float erd = er[(size_t)n * H + h];

    // ---- Phase A: online max + exp-sum over incoming edges ----
    float m_run = -1e30f, s_run = 0.f;
    for (int base = 0; base < deg; base += EPC) {
        int ei = base + esub;
        float logit = -1e30f;
        if (ei < deg) {
            int s = csr_src[beg + ei];
            float v = el[(size_t)s * H + h] + erd;
            logit = (v > 0.f) ? v : 0.2f * v;   // leaky_relu 0.2
        }
        float cmax = logit;
#pragma unroll
        for (int off = H; off < 64; off <<= 1)
            cmax = fmaxf(cmax, __shfl_xor(cmax, off));
        float nm = fmaxf(m_run, cmax);
        float ex = __expf(logit - nm);          // 0 for inactive lanes
        float csum = ex;
#pragma unroll
        for (int off = H; off < 64; off <<= 1)
            csum += __shfl_xor(csum, off);
        s_run = s_run * __expf(m_run - nm) + csum;
        m_run = nm;
    }
    const float inv_s = (deg > 0) ? 1.f / s_run : 0.f;

    // ---- Phase B: alpha-weighted gather of feat[src] ----
    float acc[CPT];
#pragma unroll
    for (int c = 0; c < CPT; ++c) acc[c] = 0.f;

    for (int base = 0; base < deg; base += EPC) {
        int ei = base + esub;
        float a = 0.f;
        if (ei < deg) {
            int s = csr_src[beg + ei];
            float v = el[(size_t)s * H + h] + erd;
            v = (v > 0.f) ? v : 0.2f * v;
            a = __expf(v - m_run) * inv_s;
        }
        int emax = min(EPC, deg - base);
        for (int i = 0; i < emax; ++i) {
            int s = csr_src[beg + base + i];    // wave-uniform broadcast load
#pragma unroll
            for (int c = 0; c < CPT; ++c) {
                int comp = lane + c * 64;
                float av = __shfl(a, i * H + comp / F);
                acc[c] = fmaf(feat[(size_t)s * D + comp], av, acc[c]);
            }
        }
    }

    // ---- epilogue: bias + activation, single write ----
#pragma unroll
    for (int c = 0; c < CPT; ++c) {
        int comp = lane + c * 64;
        float v = acc[c] + bias[comp];
        if (ACT) v = (v > 0.f) ? v : expm1f(v);   // ELU alpha=1
        out[(size_t)n * D + comp] = v;
    }
}

// ---------------------------------------------------------------------------
extern "C" void kernel_launch(void* const* d_in, const int* in_sizes, int n_in,
                              void* d_out, int out_size, void* d_ws, size_t ws_size,
                              hipStream_t stream)
{
    const float* x   = (const float*)d_in[0];
    const int*   src = (const int*)d_in[1];
    const int*   dst = (const int*)d_in[2];
    const float* W0  = (const float*)d_in[3];
    const float* al0 = (const float*)d_in[4];
    const float* ar0 = (const float*)d_in[5];
    const float* b0  = (const float*)d_in[6];
    const float* W1  = (const float*)d_in[7];
    const float* al1 = (const float*)d_in[8];
    const float* ar1 = (const float*)d_in[9];
    const float* b1  = (const float*)d_in[10];
    const float* W2  = (const float*)d_in[11];
    const float* al2 = (const float*)d_in[12];
    const float* ar2 = (const float*)d_in[13];
    const float* b2  = (const float*)d_in[14];
    float* out = (float*)d_out;

    const int N = N_NODES, E = N_EDGES;

    float* ws   = (float*)d_ws;
    float* feat = ws;                         // N*128
    float* hbuf = feat + (size_t)N * 128;     // N*128
    float* elb  = hbuf + (size_t)N * 128;     // N*8
    float* erb  = elb + (size_t)N * 8;        // N*8
    int* ibase   = (int*)(erb + (size_t)N * 8);
    int* deg     = ibase;                     // N
    int* cursor  = deg + N;                   // N
    int* offs    = cursor + N;                // N+1
    int* csr_src = offs + N + 1;              // E

    const int TB = 256;
    const int gb_rows  = (N + 7) / 8;
    const int gb_edges = (E + TB - 1) / TB;
    const int gb_nodes = (N + 3) / 4;

    // ---- CSR build (shared by all 3 layers) ----
    zero_ints<<<(2 * N + TB - 1) / TB, TB, 0, stream>>>(deg, 2 * N);  // deg+cursor
    hist_deg<<<gb_edges, TB, 0, stream>>>(dst, deg);
    scan_offsets<<<1, 1024, 0, stream>>>(deg, offs, N);
    build_csr<<<gb_edges, TB, 0, stream>>>(src, dst, offs, cursor, csr_src);

    // ---- layer 0: 256 -> 8 heads x 16, ELU ----
    gemm_attn<256, 128, 16><<<gb_rows, 128, 0, stream>>>(x, W0, al0, ar0, feat, elb, erb, N);
    node_softmax_agg<8, 16, true><<<gb_nodes, 256, 0, stream>>>(
        offs, csr_src, elb, erb, feat, b0, hbuf, N);

    // ---- layer 1: 128 -> 8 heads x 16, ELU ----
    gemm_attn<128, 128, 16><<<gb_rows, 128, 0, stream>>>(hbuf, W1, al1, ar1, feat, elb, erb, N);
    node_softmax_agg<8, 16, true><<<gb_nodes, 256, 0, stream>>>(
        offs, csr_src, elb, erb, feat, b1, hbuf, N);

    // ---- layer 2: 128 -> 1 head x 64, no act ----
    gemm_attn<128, 64, 64><<<gb_rows, 64, 0, stream>>>(hbuf, W2, al2, ar2, feat, elb, erb, N);
    node_softmax_agg<1, 64, false><<<gb_nodes, 256, 0, stream>>>(
        offs, csr_src, elb, erb, feat, b2, out, N);
}

// Round 3
// 461.866 us; speedup vs baseline: 5.0858x; 1.3186x over previous
//
#include <hip/hip_runtime.h>
#include <hip/hip_bf16.h>
#include <cstdint>

#define N_NODES 50000
#define N_EDGES 800000

// ---------------------------------------------------------------------------
// feat = X @ W  and el/er = per-head attention dots.
// 64 threads/block, RPT rows staged in LDS, CPT=DOUT/64 cols per thread:
// per k-step 8 ds_read_b128 feed 4*8*CPT FMAs (LDS-issue balanced at CPT=2).
template<int DIN, int DOUT, int F>
__global__ __launch_bounds__(64) void gemm_attn(
    const float* __restrict__ X, const float* __restrict__ W,
    const float* __restrict__ al, const float* __restrict__ ar,
    float* __restrict__ feat, float* __restrict__ el, float* __restrict__ er, int N)
{
    constexpr int RPT = 8;
    constexpr int CPT = DOUT / 64;   // cols per thread (2 for 128, 1 for 64)
    constexpr int H = DOUT / F;
    __shared__ float xs[RPT][DIN];
    const int t = threadIdx.x;       // 0..63
    const int row0 = blockIdx.x * RPT;

    // stage X rows (float4, coalesced)
    for (int idx = t; idx < RPT * (DIN / 4); idx += 64) {
        int r = idx / (DIN / 4), k4 = idx % (DIN / 4);
        int row = row0 + r;
        float4 v = (row < N) ? *reinterpret_cast<const float4*>(&X[(size_t)row * DIN + k4 * 4])
                             : make_float4(0.f, 0.f, 0.f, 0.f);
        *reinterpret_cast<float4*>(&xs[r][k4 * 4]) = v;
    }
    __syncthreads();

    float acc[CPT][RPT];
#pragma unroll
    for (int c = 0; c < CPT; ++c)
#pragma unroll
        for (int r = 0; r < RPT; ++r) acc[c][r] = 0.f;

    for (int k = 0; k < DIN; k += 4) {
        float w[CPT][4];
#pragma unroll
        for (int c = 0; c < CPT; ++c)
#pragma unroll
            for (int kk = 0; kk < 4; ++kk)
                w[c][kk] = W[(size_t)(k + kk) * DOUT + t + c * 64];
#pragma unroll
        for (int r = 0; r < RPT; ++r) {
            const float4 xv = *reinterpret_cast<const float4*>(&xs[r][k]);
#pragma unroll
            for (int c = 0; c < CPT; ++c) {
                acc[c][r] = fmaf(xv.x, w[c][0], acc[c][r]);
                acc[c][r] = fmaf(xv.y, w[c][1], acc[c][r]);
                acc[c][r] = fmaf(xv.z, w[c][2], acc[c][r]);
                acc[c][r] = fmaf(xv.w, w[c][3], acc[c][r]);
            }
        }
    }

    float alv[CPT], arv[CPT];
#pragma unroll
    for (int c = 0; c < CPT; ++c) { alv[c] = al[t + c * 64]; arv[c] = ar[t + c * 64]; }

#pragma unroll
    for (int r = 0; r < RPT; ++r) {
        int row = row0 + r;
#pragma unroll
        for (int c = 0; c < CPT; ++c) {
            float pl = acc[c][r] * alv[c];
            float pr = acc[c][r] * arv[c];
#pragma unroll
            for (int off = 1; off < F; off <<= 1) {
                pl += __shfl_xor(pl, off);
                pr += __shfl_xor(pr, off);
            }
            if (row < N) {
                feat[(size_t)row * DOUT + t + c * 64] = acc[c][r];
                if ((t & (F - 1)) == 0) {
                    int head = (t + c * 64) / F;
                    el[(size_t)row * H + head] = pl;
                    er[(size_t)row * H + head] = pr;
                }
            }
        }
    }
}

// ---------------------------------------------------------------------------
// CSR build (dst-sorted), shared by all 3 layers
__global__ void zero_ints(int* __restrict__ a, int n)
{
    int i = blockIdx.x * blockDim.x + threadIdx.x;
    if (i < n) a[i] = 0;
}

__global__ void hist_deg(const int* __restrict__ dst, int* __restrict__ deg)
{
    int e = blockIdx.x * blockDim.x + threadIdx.x;
    if (e < N_EDGES) atomicAdd(&deg[dst[e]], 1);
}

// single block, 1024 threads: exclusive scan of deg[0..n) -> offs[0..n]
__global__ __launch_bounds__(1024) void scan_offsets(
    const int* __restrict__ deg, int* __restrict__ offs, int n)
{
    __shared__ int wtot[16], wincl[16];
    __shared__ int carry_s;
    const int tid = threadIdx.x;
    const int lane = tid & 63, wid = tid >> 6;
    if (tid == 0) carry_s = 0;
    __syncthreads();
    for (int base = 0; base < n; base += 1024) {
        int i = base + tid;
        int v = (i < n) ? deg[i] : 0;
        int x = v;
#pragma unroll
        for (int off = 1; off < 64; off <<= 1) {
            int t = __shfl_up(x, off);
            if (lane >= off) x += t;
        }
        if (lane == 63) wtot[wid] = x;
        __syncthreads();
        if (tid < 16) {
            int wx = wtot[tid];
#pragma unroll
            for (int off = 1; off < 16; off <<= 1) {
                int t = __shfl_up(wx, off);
                if (tid >= off) wx += t;
            }
            wincl[tid] = wx;
        }
        __syncthreads();
        int waveExcl = (wid == 0) ? 0 : wincl[wid - 1];
        if (i < n) offs[i] = carry_s + waveExcl + (x - v);
        int total = wincl[15];
        __syncthreads();
        if (tid == 0) carry_s += total;
        __syncthreads();
    }
    if (threadIdx.x == 0) offs[n] = carry_s;
}

__global__ void build_csr(const int* __restrict__ src, const int* __restrict__ dst,
                          const int* __restrict__ offs, int* __restrict__ cursor,
                          int* __restrict__ csr_src)
{
    int e = blockIdx.x * blockDim.x + threadIdx.x;
    if (e >= N_EDGES) return;
    int d = dst[e];
    int p = offs[d] + atomicAdd(&cursor[d], 1);
    csr_src[p] = src[e];
}

// ---------------------------------------------------------------------------
// Fused flash-style softmax + aggregation per dst node. One wave per node.
// Single pass: online max/sum with accumulator rescale; feat gathers batched
// SB=8 edges deep for memory-level parallelism; tail padded via ex=0.
template<int H, int F, bool ACT>
__global__ __launch_bounds__(256) void node_flash_agg(
    const int* __restrict__ offs, const int* __restrict__ csr_src,
    const float* __restrict__ el, const float* __restrict__ er,
    const float* __restrict__ feat, const float* __restrict__ bias,
    float* __restrict__ out, int N)
{
    constexpr int D = H * F;
    constexpr int CPT = D / 64;     // components per lane (2 or 1)
    constexpr int EPC = 64 / H;     // edges per chunk (8 or 64)
    constexpr int SB = 8;           // feat-load batch depth

    const int wid = threadIdx.x >> 6;
    const int lane = threadIdx.x & 63;
    const int n = blockIdx.x * 4 + wid;
    if (n >= N) return;

    const int beg = offs[n];
    const int deg = offs[n + 1] - beg;

    const int h = lane % H;
    const int esub = lane / H;
    const float erd = er[(size_t)n * H + h];

    float m_run = -1e30f, s_run = 0.f;
    float acc[CPT];
#pragma unroll
    for (int c = 0; c < CPT; ++c) acc[c] = 0.f;

    for (int base = 0; base < deg; base += EPC) {
        int ei = base + esub;
        int s_mine = csr_src[beg + min(ei, deg - 1)];   // clamped for padding
        float v = el[(size_t)s_mine * H + h] + erd;
        v = (v > 0.f) ? v : 0.2f * v;                   // leaky_relu 0.2
        float logit = (ei < deg) ? v : -1e30f;

        float cmax = logit;
#pragma unroll
        for (int off = H; off < 64; off <<= 1)
            cmax = fmaxf(cmax, __shfl_xor(cmax, off));
        float nm = fmaxf(m_run, cmax);
        float scale = __expf(m_run - nm);               // 0 on first chunk
        float ex = __expf(logit - nm);                  // 0 for padded lanes
        float csum = ex;
#pragma unroll
        for (int off = H; off < 64; off <<= 1)
            csum += __shfl_xor(csum, off);
        s_run = s_run * scale + csum;
        m_run = nm;

#pragma unroll
        for (int c = 0; c < CPT; ++c)
            acc[c] *= __shfl(scale, (lane + c * 64) / F);

        int active = min(EPC, deg - base);
        for (int g = 0; g < active; g += SB) {
            float fv[SB][CPT];
#pragma unroll
            for (int ii = 0; ii < SB; ++ii) {
                int sl = __shfl(s_mine, (g + ii) * H);  // edge g+ii src row
#pragma unroll
                for (int c = 0; c < CPT; ++c)
                    fv[ii][c] = feat[(size_t)sl * D + lane + c * 64];
            }
#pragma unroll
            for (int ii = 0; ii < SB; ++ii)
#pragma unroll
                for (int c = 0; c < CPT; ++c) {
                    float exb = __shfl(ex, (g + ii) * H + (lane + c * 64) / F);
                    acc[c] = fmaf(fv[ii][c], exb, acc[c]);
                }
        }
    }

    const float inv = (s_run > 0.f) ? 1.f / s_run : 0.f;
#pragma unroll
    for (int c = 0; c < CPT; ++c) {
        int comp = lane + c * 64;
        float v = acc[c] * __shfl(inv, comp / F) + bias[comp];
        if (ACT) v = (v > 0.f) ? v : expm1f(v);         // ELU alpha=1
        out[(size_t)n * D + comp] = v;
    }
}

// ---------------------------------------------------------------------------
extern "C" void kernel_launch(void* const* d_in, const int* in_sizes, int n_in,
                              void* d_out, int out_size, void* d_ws, size_t ws_size,
                              hipStream_t stream)
{
    const float* x   = (const float*)d_in[0];
    const int*   src = (const int*)d_in[1];
    const int*   dst = (const int*)d_in[2];
    const float* W0  = (const float*)d_in[3];
    const float* al0 = (const float*)d_in[4];
    const float* ar0 = (const float*)d_in[5];
    const float* b0  = (const float*)d_in[6];
    const float* W1  = (const float*)d_in[7];
    const float* al1 = (const float*)d_in[8];
    const float* ar1 = (const float*)d_in[9];
    const float* b1  = (const float*)d_in[10];
    const float* W2  = (const float*)d_in[11];
    const float* al2 = (const float*)d_in[12];
    const float* ar2 = (const float*)d_in[13];
    const float* b2  = (const float*)d_in[14];
    float* out = (float*)d_out;

    const int N = N_NODES, E = N_EDGES;

    float* ws   = (float*)d_ws;
    float* feat = ws;                         // N*128
    float* hbuf = feat + (size_t)N * 128;     // N*128
    float* elb  = hbuf + (size_t)N * 128;     // N*8
    float* erb  = elb + (size_t)N * 8;        // N*8
    int* ibase   = (int*)(erb + (size_t)N * 8);
    int* deg     = ibase;                     // N
    int* cursor  = deg + N;                   // N
    int* offs    = cursor + N;                // N+1
    int* csr_src = offs + N + 1;              // E

    const int TB = 256;
    const int gb_rows  = (N + 7) / 8;
    const int gb_edges = (E + TB - 1) / TB;
    const int gb_nodes = (N + 3) / 4;

    // ---- CSR build (shared by all 3 layers) ----
    zero_ints<<<(2 * N + TB - 1) / TB, TB, 0, stream>>>(deg, 2 * N);  // deg+cursor
    hist_deg<<<gb_edges, TB, 0, stream>>>(dst, deg);
    scan_offsets<<<1, 1024, 0, stream>>>(deg, offs, N);
    build_csr<<<gb_edges, TB, 0, stream>>>(src, dst, offs, cursor, csr_src);

    // ---- layer 0: 256 -> 8 heads x 16, ELU ----
    gemm_attn<256, 128, 16><<<gb_rows, 64, 0, stream>>>(x, W0, al0, ar0, feat, elb, erb, N);
    node_flash_agg<8, 16, true><<<gb_nodes, 256, 0, stream>>>(
        offs, csr_src, elb, erb, feat, b0, hbuf, N);

    // ---- layer 1: 128 -> 8 heads x 16, ELU ----
    gemm_attn<128, 128, 16><<<gb_rows, 64, 0, stream>>>(hbuf, W1, al1, ar1, feat, elb, erb, N);
    node_flash_agg<8, 16, true><<<gb_nodes, 256, 0, stream>>>(
        offs, csr_src, elb, erb, feat, b1, hbuf, N);

    // ---- layer 2: 128 -> 1 head x 64, no act ----
    gemm_attn<128, 64, 64><<<gb_rows, 64, 0, stream>>>(hbuf, W2, al2, ar2, feat, elb, erb, N);
    node_flash_agg<1, 64, false><<<gb_nodes, 256, 0, stream>>>(
        offs, csr_src, elb, erb, feat, b2, out, N);
}